// Round 1
// baseline (943.669 us; speedup 1.0000x reference)
//
#include <hip/hip_runtime.h>
#include <math.h>

// GFlowNet actor rollout on MI355X — round 3.
// One 64-lane wave per rollout, 4 waves/block, no in-loop barriers.
// vs round 2: (a) LayerNorm mean/var fused into ONE butterfly (sum x, sum x^2
// carried together; var = E[x^2]-mu^2), removing a sequential cross-lane
// reduction from every step; (b) score-matvec broadcast switched from
// 2x readlane + cndmask to a single width-32 __shfl (lanes 0-31 read hid[i],
// lanes 32-63 read hid[32+i]).

namespace {
constexpr int Bx = 4096;
constexpr int Dx = 32;
constexpr int Hx = 64;
constexpr int Tx = 8;
constexpr float NEGV   = -1e9f;
constexpr float LN_EPS = 1e-5f;
constexpr float MIN_T  = 1e-5f;
} // namespace

__device__ __forceinline__ float wsum(float v) {
#pragma unroll
  for (int m = 32; m >= 1; m >>= 1) v += __shfl_xor(v, m);
  return v;
}
__device__ __forceinline__ float wmax(float v) {
#pragma unroll
  for (int m = 32; m >= 1; m >>= 1) v = fmaxf(v, __shfl_xor(v, m));
  return v;
}
// wave-uniform broadcast of lane i's value (VALU v_readlane; i is a literal
// after full unroll). Avoids the DS pipe and any LDS ordering assumptions.
__device__ __forceinline__ float lanebc(float v, int i) {
  return __int_as_float(__builtin_amdgcn_readlane(__float_as_int(v), i));
}

__global__ __launch_bounds__(256, 4) void gflow_rollout(
    const float* __restrict__ q_tokens,      // [B,H]
    const int*   __restrict__ nbr_node,      // [NTOT,D]
    const int*   __restrict__ start_nodes,   // [B]
    const int*   __restrict__ edge_valid,    // [NTOT,D]
    const float* __restrict__ action_keys,   // [NTOT,D,H]
    const float* __restrict__ W_init,        // [H,H]
    const float* __restrict__ W_h,           // [H,H]
    const float* __restrict__ W_k,           // [H,H]
    const float* __restrict__ ln_gamma,      // [H+2]
    const float* __restrict__ ln_beta,       // [H+2]
    const float* __restrict__ stop_w,        // [H+2]
    const float* __restrict__ stop_b,        // [1]
    const float* __restrict__ temperature,   // [1]
    float* __restrict__ out)                 // [B*9 | B | B*9 | B] as f32
{
  __shared__ float Wh_s[Hx * Hx];   // 16KB
  __shared__ float Wk_s[Hx * Hx];   // 16KB

  const int tid   = threadIdx.x;
  const int lane  = tid & 63;
  const int wslot = tid >> 6;
  const int b     = blockIdx.x * 4 + wslot;
  const int d     = lane & 31;
  const int half  = lane >> 5;

  int cur = start_nodes[b];

  // ---- issue t=0 gather immediately (overlaps W staging + init matvec) ----
  float kf[32];                 // this lane's half-row of keys (32 floats)
  {
    const float4* kp =
        (const float4*)(action_keys + ((size_t)cur * Dx + d) * Hx + half * 32);
#pragma unroll
    for (int c = 0; c < 8; ++c) ((float4*)kf)[c] = kp[c];
  }
  // fused aux row: lanes 0..31 -> edge_valid[cur][d], lanes 32..63 -> nbr[cur][d]
  const int* evn_base = (lane < Dx) ? edge_valid : nbr_node;
  int evnb = evn_base[(size_t)cur * Dx + d];

  // ---- stage W_h, W_k into LDS (whole block) ----
  {
    const float4* sh = (const float4*)W_h;
    const float4* sk = (const float4*)W_k;
    float4* dh = (float4*)Wh_s;
    float4* dk = (float4*)Wk_s;
#pragma unroll
    for (int i = 0; i < 4; ++i) {
      dh[tid + i * 256] = sh[tid + i * 256];
      dk[tid + i * 256] = sk[tid + i * 256];
    }
  }

  // ---- per-lane constants ----
  const float g_j  = ln_gamma[lane];
  const float be_j = ln_beta[lane];
  const float w_j  = stop_w[lane];
  const float g64 = ln_gamma[64], g65 = ln_gamma[65];
  const float b64 = ln_beta[64],  b65 = ln_beta[65];
  const float w64 = stop_w[64],   w65 = stop_w[65];
  const float sb  = stop_b[0];
  const float tcl = fmaxf(temperature[0], MIN_T);

  // ---- hidden0 = tanh(q @ W_init)  (global W_init, coalesced, L2-hot) ----
  float hid;
  {
    const float qv = q_tokens[b * Hx + lane];
    float acc0 = 0.f;
#pragma unroll
    for (int i = 0; i < Hx; ++i)
      acc0 = fmaf(lanebc(qv, i), W_init[i * Hx + lane], acc0);
    hid = tanhf(acc0);
  }

  __syncthreads();  // the ONLY barrier: W_h/W_k staged before first matvec

  float lp_total = 0.f;
  int   nmoves   = 0;
  int   tstop    = Tx;  // loop always breaks via chose_stop by t=Tx

  float* out_act = out + (size_t)b * (Tx + 1);
  float* out_lps = out + (size_t)Bx * (Tx + 1) + Bx + (size_t)b * (Tx + 1);

  for (int t = 0; t <= Tx; ++t) {
    // ---- scores[d] = <hidden, keys[d]> (skip at horizon: fully masked) ----
    float score = 0.f;
    if (t < Tx) {
      float part = 0.f;
#pragma unroll
      for (int i = 0; i < 32; ++i) {
        // width-32 shuffle: lanes 0-31 read hid[i], lanes 32-63 read hid[32+i]
        const float hv = __shfl(hid, i, 32);
        part = fmaf(kf[i], hv, part);
      }
      score = part + __shfl_xor(part, 32);
    }

    const bool validd = (lane < Dx) && (evnb != 0) && (t < Tx);
    const unsigned long long vm = __ballot(validd);
    const bool has_edge = (vm != 0ULL);

    // ---- layernorm(concat(hidden, t/T, has_edge)) . stop_w + stop_b ----
    // One fused butterfly carrying (sum x, sum x^2); var = E[x^2] - mu^2.
    const float sf = (float)t / (float)Tx;
    const float he = has_edge ? 1.0f : 0.0f;
    float s1 = hid;
    float s2 = hid * hid;
    if (lane == 0) { s1 += sf; s2 = fmaf(sf, sf, s2); }
    if (lane == 1) { s1 += he; s2 = fmaf(he, he, s2); }
#pragma unroll
    for (int m = 32; m >= 1; m >>= 1) {
      s1 += __shfl_xor(s1, m);
      s2 += __shfl_xor(s2, m);
    }
    const float mu   = s1 / 66.0f;
    const float var  = s2 / 66.0f - mu * mu;
    const float rstd = rsqrtf(var + LN_EPS);
    const float dcj  = hid - mu;
    float contrib = (dcj * rstd * g_j + be_j) * w_j;
    if (lane == 0) contrib += ((sf - mu) * rstd * g64 + b64) * w64;
    if (lane == 1) contrib += ((he - mu) * rstd * g65 + b65) * w65;
    const float stop_logit = wsum(contrib) + sb;

    // ---- logits / softmax / argmax (first-max = jnp.argmax semantics) ----
    float lg;
    if (lane < Dx)       lg = (validd ? score : NEGV) / tcl;
    else if (lane == Dx) lg = stop_logit / tcl;
    else                 lg = -INFINITY;
    const float mx = wmax(lg);
    const float ex = (lane <= Dx) ? expf(lg - mx) : 0.f;
    const float se = wsum(ex);
    const unsigned long long am = __ballot(lg == mx);
    const int   action = __ffsll(am) - 1;
    const float lga    = __shfl(lg, action);
    const float lp     = lga - mx - logf(se);

    const bool chose_stop = (action == Dx);
    const int  a = min(action, Dx - 1);

    if (lane == 0) {
      out_act[t] = chose_stop ? -1.0f : (float)(cur * Dx + a);
      out_lps[t] = lp;
    }
    lp_total += lp;

    if (chose_stop) { tstop = t; break; }
    nmoves++;

    // ---- selected key row (256B, L1-hot: subset of the 8KB just gathered) ----
    const float selv = action_keys[((size_t)cur * Dx + a) * Hx + lane];

    // ---- advance; issue NEXT gather before the matvec (latency overlap) ----
    cur = __shfl(evnb, Dx + a);   // nbr row rode along with the gather
    if (t + 1 < Tx) {
      const float4* kp =
          (const float4*)(action_keys + ((size_t)cur * Dx + d) * Hx + half * 32);
#pragma unroll
      for (int c = 0; c < 8; ++c) ((float4*)kf)[c] = kp[c];
      evnb = evn_base[(size_t)cur * Dx + d];
    }

    // ---- new_hidden = tanh(hidden @ W_h + sel @ W_k) ----
    float a1 = 0.f, a2 = 0.f;
#pragma unroll
    for (int i = 0; i < Hx; ++i) {
      a1 = fmaf(lanebc(hid,  i), Wh_s[i * Hx + lane], a1);
      a2 = fmaf(lanebc(selv, i), Wk_s[i * Hx + lane], a2);
    }
    hid = tanhf(a1 + a2);
  }

  // ---- epilogue: fill post-stop steps, totals ----
  if (lane == 0) {
    for (int t = tstop + 1; t <= Tx; ++t) { out_act[t] = -1.0f; out_lps[t] = 0.f; }
    out[(size_t)Bx * (Tx + 1) + b] = lp_total;                            // log_pf_total
    out[(size_t)Bx * (Tx + 1) + Bx + (size_t)Bx * (Tx + 1) + b] = (float)nmoves; // num_moves
  }
}

extern "C" void kernel_launch(void* const* d_in, const int* in_sizes, int n_in,
                              void* d_out, int out_size, void* d_ws, size_t ws_size,
                              hipStream_t stream) {
  const float* q_tokens    = (const float*)d_in[0];
  const int*   nbr_node    = (const int*)d_in[1];
  const int*   start_nodes = (const int*)d_in[2];
  const int*   edge_valid  = (const int*)d_in[3];
  const float* action_keys = (const float*)d_in[4];
  const float* W_init      = (const float*)d_in[5];
  const float* W_h         = (const float*)d_in[6];
  const float* W_k         = (const float*)d_in[7];
  const float* ln_gamma    = (const float*)d_in[8];
  const float* ln_beta     = (const float*)d_in[9];
  const float* stop_w      = (const float*)d_in[10];
  const float* stop_b      = (const float*)d_in[11];
  const float* temperature = (const float*)d_in[12];
  float* out = (float*)d_out;

  gflow_rollout<<<dim3(Bx / 4), dim3(256), 0, stream>>>(
      q_tokens, nbr_node, start_nodes, edge_valid, action_keys,
      W_init, W_h, W_k, ln_gamma, ln_beta, stop_w, stop_b, temperature, out);
}

// Round 2
// 937.694 us; speedup vs baseline: 1.0064x; 1.0064x over previous
//
#include <hip/hip_runtime.h>
#include <math.h>

// GFlowNet actor rollout on MI355X — round 4.
// One 64-lane wave per rollout, 4 waves/block, no in-loop barriers.
// vs round 3:
//  (a) action_keys gather is now WAVE-CONTIGUOUS per instruction: instr c reads
//      bytes [c*1024, c*1024+1024) of the 8KB row, lane l takes 16B at l*16.
//      (Old layout read 64 lines/instr using 16B of each -> L1/L2 thrash ->
//      4-8x HBM overfetch; this was the ~420us residual theory.)
//      Lane l therefore holds K[d=4c+(l>>4)][h=4(l&15)+j]; the score is built
//      as per-lane partials + DPP row_shr scan over 16-lane rows + one
//      ds_bpermute per chunk + a cndmask tree that lands score[d] on lane d
//      (preserving exact argmax tie-break semantics).
//  (b) all wave reductions (LN mean/var, stop dot, softmax max/sum) use DPP
//      row_shr/bcast chains + v_readlane63 -> SGPR broadcast (VALU) instead of
//      __shfl_xor butterflies (DS).
//  (c) W_h/W_k interleaved as float2 pairs in LDS -> 64 ds_read_b64 per matvec
//      pair instead of 128 ds_read_b32.

namespace {
constexpr int Bx = 4096;
constexpr int Dx = 32;
constexpr int Hx = 64;
constexpr int Tx = 8;
constexpr float NEGV   = -1e9f;
constexpr float LN_EPS = 1e-5f;
constexpr float MIN_T  = 1e-5f;
} // namespace

// wave-uniform broadcast of lane i's value (v_readlane; i literal or uniform).
__device__ __forceinline__ float lanebc(float v, int i) {
  return __int_as_float(__builtin_amdgcn_readlane(__float_as_int(v), i));
}
__device__ __forceinline__ float bperm_f(int addr, float v) {
  return __int_as_float(__builtin_amdgcn_ds_bpermute(addr, __float_as_int(v)));
}
template <int CTRL, int RM, bool BC>
__device__ __forceinline__ float dpp_mov(float old_, float src) {
  return __int_as_float(__builtin_amdgcn_update_dpp(
      __float_as_int(old_), __float_as_int(src), CTRL, RM, 0xF, BC));
}
// Full-wave sum -> wave-uniform scalar (canonical GCN DPP reduce, lane63).
__device__ __forceinline__ float dpp_wsum(float v) {
  v += dpp_mov<0x111, 0xF, true>(0.f, v);   // row_shr:1
  v += dpp_mov<0x112, 0xF, true>(0.f, v);   // row_shr:2
  v += dpp_mov<0x114, 0xF, true>(0.f, v);   // row_shr:4
  v += dpp_mov<0x118, 0xF, true>(0.f, v);   // row_shr:8
  v += dpp_mov<0x142, 0xA, true>(0.f, v);   // row_bcast15 -> rows 1,3
  v += dpp_mov<0x143, 0xC, true>(0.f, v);   // row_bcast31 -> rows 2,3
  return lanebc(v, 63);
}
// Full-wave max -> wave-uniform scalar.
__device__ __forceinline__ float dpp_wmax(float v) {
  v = fmaxf(v, dpp_mov<0x111, 0xF, false>(v, v));
  v = fmaxf(v, dpp_mov<0x112, 0xF, false>(v, v));
  v = fmaxf(v, dpp_mov<0x114, 0xF, false>(v, v));
  v = fmaxf(v, dpp_mov<0x118, 0xF, false>(v, v));
  v = fmaxf(v, dpp_mov<0x142, 0xA, false>(v, v));
  v = fmaxf(v, dpp_mov<0x143, 0xC, false>(v, v));
  return lanebc(v, 63);
}
// 16-lane row inclusive scan-sum; lane 16r+15 holds the row total.
__device__ __forceinline__ float dpp_rowsum(float v) {
  v += dpp_mov<0x111, 0xF, true>(0.f, v);
  v += dpp_mov<0x112, 0xF, true>(0.f, v);
  v += dpp_mov<0x114, 0xF, true>(0.f, v);
  v += dpp_mov<0x118, 0xF, true>(0.f, v);
  return v;
}

__global__ __launch_bounds__(256, 4) void gflow_rollout(
    const float* __restrict__ q_tokens,      // [B,H]
    const int*   __restrict__ nbr_node,      // [NTOT,D]
    const int*   __restrict__ start_nodes,   // [B]
    const int*   __restrict__ edge_valid,    // [NTOT,D]
    const float* __restrict__ action_keys,   // [NTOT,D,H]
    const float* __restrict__ W_init,        // [H,H]
    const float* __restrict__ W_h,           // [H,H]
    const float* __restrict__ W_k,           // [H,H]
    const float* __restrict__ ln_gamma,      // [H+2]
    const float* __restrict__ ln_beta,       // [H+2]
    const float* __restrict__ stop_w,        // [H+2]
    const float* __restrict__ stop_b,        // [1]
    const float* __restrict__ temperature,   // [1]
    float* __restrict__ out)                 // [B*9 | B | B*9 | B] as f32
{
  // Interleaved {W_h, W_k} pairs: P_s[f] = {W_h[f], W_k[f]} -> ds_read_b64.
  __shared__ __align__(16) float2 P_s[Hx * Hx];   // 32KB

  const int tid   = threadIdx.x;
  const int lane  = tid & 63;
  const int wslot = tid >> 6;
  const int b     = blockIdx.x * 4 + wslot;
  const int d     = lane & 31;

  int cur = start_nodes[b];

  // ---- t=0 gather: 8 instructions, each a contiguous 1KB (lane l -> l*16B) --
  float4 kf4[8];
  {
    const float4* kp = (const float4*)(action_keys + (size_t)cur * (Dx * Hx));
#pragma unroll
    for (int c = 0; c < 8; ++c) kf4[c] = kp[c * 64 + lane];
  }
  // fused aux row: lanes 0..31 -> edge_valid[cur][d], lanes 32..63 -> nbr[cur][d]
  const int* evn_base = (lane < Dx) ? edge_valid : nbr_node;
  int evnb = evn_base[(size_t)cur * Dx + d];

  // ---- stage interleaved W pairs into LDS (whole block) ----
  {
    const float4* sh = (const float4*)W_h;
    const float4* sk = (const float4*)W_k;
#pragma unroll
    for (int i = 0; i < 4; ++i) {
      const int idx = tid + i * 256;            // float4 index 0..1023
      const float4 h4 = sh[idx];
      const float4 k4 = sk[idx];
      float4* dst = (float4*)(P_s + (size_t)idx * 4);
      dst[0] = make_float4(h4.x, k4.x, h4.y, k4.y);
      dst[1] = make_float4(h4.z, k4.z, h4.w, k4.w);
    }
  }

  // ---- per-lane constants ----
  const float g_j  = ln_gamma[lane];
  const float be_j = ln_beta[lane];
  const float w_j  = stop_w[lane];
  const float g64 = ln_gamma[64], g65 = ln_gamma[65];
  const float b64 = ln_beta[64],  b65 = ln_beta[65];
  const float w64 = stop_w[64],   w65 = stop_w[65];
  const float sb  = stop_b[0];
  const float tcl = fmaxf(temperature[0], MIN_T);

  // score-pipeline address constants
  const int aq  = (lane & 15) << 4;             // 4 * (4*(lane&15)): hq gather
  const int as_ = ((lane & 3) << 6) + 60;       // 4 * (16*(lane&3) + 15)
  const bool sb0 = (lane & 4)  != 0;            // bit0 of c = lane>>2
  const bool sb1 = (lane & 8)  != 0;
  const bool sb2 = (lane & 16) != 0;

  // ---- hidden0 = tanh(q @ W_init)  (global W_init, coalesced, L2-hot) ----
  float hid;
  {
    const float qv = q_tokens[b * Hx + lane];
    float acc0 = 0.f;
#pragma unroll
    for (int i = 0; i < Hx; ++i)
      acc0 = fmaf(lanebc(qv, i), W_init[i * Hx + lane], acc0);
    hid = tanhf(acc0);
  }

  __syncthreads();  // the ONLY barrier: P_s staged before first matvec

  float lp_total = 0.f;
  int   nmoves   = 0;
  int   tstop    = Tx;

  float* out_act = out + (size_t)b * (Tx + 1);
  float* out_lps = out + (size_t)Bx * (Tx + 1) + Bx + (size_t)b * (Tx + 1);

  for (int t = 0; t <= Tx; ++t) {
    // ---- scores: partials in gather layout, DPP row-sum, redistribute ----
    float score = NEGV;
    if (t < Tx) {
      // hq[j] = hid[4*(lane&15)+j]
      const float hq0 = bperm_f(aq,      hid);
      const float hq1 = bperm_f(aq + 4,  hid);
      const float hq2 = bperm_f(aq + 8,  hid);
      const float hq3 = bperm_f(aq + 12, hid);
      float part[8];
#pragma unroll
      for (int c = 0; c < 8; ++c)
        part[c] = fmaf(kf4[c].w, hq3,
                  fmaf(kf4[c].z, hq2,
                  fmaf(kf4[c].y, hq1, kf4[c].x * hq0)));
      // row scan-sum: lane 16g+15 holds score[4c+g]
#pragma unroll
      for (int c = 0; c < 8; ++c) part[c] = dpp_rowsum(part[c]);
      // every lane pulls score[4c + (lane&3)] from lane 16*(lane&3)+15
      float bs[8];
#pragma unroll
      for (int c = 0; c < 8; ++c) bs[c] = bperm_f(as_, part[c]);
      // select chunk c = (lane>>2)&7 -> lane d holds score[d] (d = lane < 32)
      const float t01 = sb0 ? bs[1] : bs[0];
      const float t23 = sb0 ? bs[3] : bs[2];
      const float t45 = sb0 ? bs[5] : bs[4];
      const float t67 = sb0 ? bs[7] : bs[6];
      const float tA  = sb1 ? t23 : t01;
      const float tB  = sb1 ? t67 : t45;
      score = sb2 ? tB : tA;
    }

    const bool validd = (lane < Dx) && (evnb != 0) && (t < Tx);
    const unsigned long long vm = __ballot(validd);
    const bool has_edge = (vm != 0ULL);

    // ---- layernorm(concat(hidden, t/T, has_edge)) . stop_w + stop_b ----
    const float sf = (float)t / (float)Tx;
    const float he = has_edge ? 1.0f : 0.0f;
    float xs = hid;
    float xq = hid * hid;
    if (lane == 0) { xs += sf; xq = fmaf(sf, sf, xq); }
    if (lane == 1) { xs += he; xq = fmaf(he, he, xq); }
    const float mu   = dpp_wsum(xs) * (1.0f / 66.0f);
    const float var  = dpp_wsum(xq) * (1.0f / 66.0f) - mu * mu;
    const float rstd = rsqrtf(var + LN_EPS);
    const float dcj  = hid - mu;
    float contrib = (dcj * rstd * g_j + be_j) * w_j;
    if (lane == 0) contrib += ((sf - mu) * rstd * g64 + b64) * w64;
    if (lane == 1) contrib += ((he - mu) * rstd * g65 + b65) * w65;
    const float stop_logit = dpp_wsum(contrib) + sb;

    // ---- logits / softmax / argmax (first-max = jnp.argmax semantics) ----
    float lg;
    if (lane < Dx)       lg = (validd ? score : NEGV) / tcl;
    else if (lane == Dx) lg = stop_logit / tcl;
    else                 lg = -INFINITY;
    const float mx = dpp_wmax(lg);
    const float ex = (lane <= Dx) ? expf(lg - mx) : 0.f;
    const float se = dpp_wsum(ex);
    const unsigned long long am = __ballot(lg == mx);
    const int   action = __ffsll(am) - 1;
    const float lga    = lanebc(lg, action);
    const float lp     = lga - mx - logf(se);

    const bool chose_stop = (action == Dx);
    const int  a = min(action, Dx - 1);

    if (lane == 0) {
      out_act[t] = chose_stop ? -1.0f : (float)(cur * Dx + a);
      out_lps[t] = lp;
    }
    lp_total += lp;

    if (chose_stop) { tstop = t; break; }
    nmoves++;

    // ---- selected key row (256B contiguous, L2-hot: just gathered) ----
    const float selv = action_keys[((size_t)cur * Dx + a) * Hx + lane];

    // ---- advance; issue NEXT gather before the matvec (latency overlap) ----
    cur = __builtin_amdgcn_readlane(evnb, Dx + a);  // nbr rode along
    if (t + 1 < Tx) {
      const float4* kp = (const float4*)(action_keys + (size_t)cur * (Dx * Hx));
#pragma unroll
      for (int c = 0; c < 8; ++c) kf4[c] = kp[c * 64 + lane];
      evnb = evn_base[(size_t)cur * Dx + d];
    }

    // ---- new_hidden = tanh(hidden @ W_h + sel @ W_k), b64 paired reads ----
    float a1 = 0.f, a2 = 0.f, c1 = 0.f, c2 = 0.f;
#pragma unroll
    for (int i = 0; i < Hx; i += 2) {
      const float2 wA = P_s[i * 64 + lane];
      const float2 wB = P_s[(i + 1) * 64 + lane];
      a1 = fmaf(lanebc(hid,  i),     wA.x, a1);
      a2 = fmaf(lanebc(selv, i),     wA.y, a2);
      c1 = fmaf(lanebc(hid,  i + 1), wB.x, c1);
      c2 = fmaf(lanebc(selv, i + 1), wB.y, c2);
    }
    hid = tanhf((a1 + c1) + (a2 + c2));
  }

  // ---- epilogue: fill post-stop steps, totals ----
  if (lane == 0) {
    for (int t = tstop + 1; t <= Tx; ++t) { out_act[t] = -1.0f; out_lps[t] = 0.f; }
    out[(size_t)Bx * (Tx + 1) + b] = lp_total;                                   // log_pf_total
    out[(size_t)Bx * (Tx + 1) + Bx + (size_t)Bx * (Tx + 1) + b] = (float)nmoves; // num_moves
  }
}

extern "C" void kernel_launch(void* const* d_in, const int* in_sizes, int n_in,
                              void* d_out, int out_size, void* d_ws, size_t ws_size,
                              hipStream_t stream) {
  const float* q_tokens    = (const float*)d_in[0];
  const int*   nbr_node    = (const int*)d_in[1];
  const int*   start_nodes = (const int*)d_in[2];
  const int*   edge_valid  = (const int*)d_in[3];
  const float* action_keys = (const float*)d_in[4];
  const float* W_init      = (const float*)d_in[5];
  const float* W_h         = (const float*)d_in[6];
  const float* W_k         = (const float*)d_in[7];
  const float* ln_gamma    = (const float*)d_in[8];
  const float* ln_beta     = (const float*)d_in[9];
  const float* stop_w      = (const float*)d_in[10];
  const float* stop_b      = (const float*)d_in[11];
  const float* temperature = (const float*)d_in[12];
  float* out = (float*)d_out;

  gflow_rollout<<<dim3(Bx / 4), dim3(256), 0, stream>>>(
      q_tokens, nbr_node, start_nodes, edge_valid, action_keys,
      W_init, W_h, W_k, ln_gamma, ln_beta, stop_w, stop_b, temperature, out);
}